// Round 5
// baseline (368.307 us; speedup 1.0000x reference)
//
#include <hip/hip_runtime.h>

// data: [4, 3, 1024, 1024] fp32; NX=64, scale=16, ny=64, N=4096, p=15
// out = concat(A[4,4096,4096], data) flat fp32
#define BB 4
#define CC 3
#define HH 1024
#define WW 1024
#define NXG 64
#define NYG 64
#define SCALE 16
#define PP 15
#define NNODE 4096

static const long long A_ELEMS    = (long long)BB * NNODE * NNODE;   // 67,108,864
static const long long DATA_ELEMS = (long long)BB * CC * HH * WW;    // 12,582,912

#define ROW_BLOCKS 4096     // 4 row-waves/block -> 16384 = BB*NNODE rows
#define COPY_BLOCKS 1024

// One kernel. Row-waves: (A) stream the pure-zero float4s of their 16 KB
// A-row FIRST (no data dependency -> stores fill the vm queue), (B) gather
// the <=4 edge affinities redundantly (both endpoint rows compute the same
// value bitwise-identically -> no ordering needed), (C) store the <=4
// float4s that carry edge values, merging L/R when they share a float4.
// Copy-blocks stream data -> out tail in the same launch.
__global__ __launch_bounds__(256) void fused2(const float* __restrict__ data,
                                              float* __restrict__ out) {
    if (blockIdx.x >= ROW_BLOCKS) {
        long long i = (long long)(blockIdx.x - ROW_BLOCKS) * 256 + threadIdx.x;
        const long long stride = (long long)COPY_BLOCKS * 256;
        const float4* __restrict__ src = (const float4*)data;
        float4* __restrict__ dst = (float4*)(out + A_ELEMS);
        const long long nvec = DATA_ELEMS / 4;
        for (; i < nvec; i += stride) dst[i] = src[i];
        return;
    }

    const int wid  = blockIdx.x * 4 + (threadIdx.x >> 6);  // 0..16383
    const int lane = threadIdx.x & 63;
    const int b = wid >> 12;
    const int n = wid & (NNODE - 1);
    const int y = n >> 6, x = n & 63;

    const bool hasUp = y > 0, hasDown = y < NYG - 1;
    const bool hasLeft = x > 0, hasRight = x < NXG - 1;

    // wave-uniform: which of the 16 store iterations contain an edge value
    const int kUp    = __builtin_amdgcn_readfirstlane(hasUp    ? ((n - 64) >> 8) : -1);
    const int kDown  = __builtin_amdgcn_readfirstlane(hasDown  ? ((n + 64) >> 8) : -1);
    const int kLeft  = __builtin_amdgcn_readfirstlane(hasLeft  ? ((n - 1)  >> 8) : -1);
    const int kRight = __builtin_amdgcn_readfirstlane(hasRight ? ((n + 1)  >> 8) : -1);

    float4* rowp = (float4*)(out + ((long long)b * NNODE + n) * NNODE);
    const float4 z = make_float4(0.f, 0.f, 0.f, 0.f);

    // -------- Phase A: dependency-free zero stream (13..16 of 16 stores)
    #pragma unroll
    for (int k = 0; k < 16; ++k) {
        if (k != kUp && k != kDown && k != kLeft && k != kRight)
            rowp[k * 64 + lane] = z;
    }

    // -------- Phase B: gather the <=4 edge affinities (redundant compute)
    const int r = lane >> 2;   // patch row 0..15 (15 inactive)
    const int q = lane & 3;    // float4 quad within the 16-wide cell
    const float* cell = data + (((long long)(b * CC)) * HH + (long long)y * SCALE) * WW
                             + x * SCALE;
    const long long CH = (long long)HH * WW;

    float sUp = 0.f, sDown = 0.f, sLeft = 0.f, sRight = 0.f;
    if (r < PP) {
        #pragma unroll
        for (int c = 0; c < CC; ++c) {
            const float* p = cell + (long long)c * CH + (long long)r * WW + q * 4;
            const float4 cf = *(const float4*)p;
            const bool keepW = (q != 3);   // col 15 excluded from patches
            if (hasUp) {
                float4 nf = *(const float4*)(p - (long long)SCALE * WW);
                float d = fabsf(nf.x - cf.x) + fabsf(nf.y - cf.y) + fabsf(nf.z - cf.z);
                if (keepW) d += fabsf(nf.w - cf.w);
                sUp += d;
            }
            if (hasDown) {
                float4 nf = *(const float4*)(p + (long long)SCALE * WW);
                float d = fabsf(nf.x - cf.x) + fabsf(nf.y - cf.y) + fabsf(nf.z - cf.z);
                if (keepW) d += fabsf(nf.w - cf.w);
                sDown += d;
            }
            if (hasLeft) {
                float4 nf = *(const float4*)(p - SCALE);
                float d = fabsf(nf.x - cf.x) + fabsf(nf.y - cf.y) + fabsf(nf.z - cf.z);
                if (keepW) d += fabsf(nf.w - cf.w);
                sLeft += d;
            }
            if (hasRight) {
                float4 nf = *(const float4*)(p + SCALE);
                float d = fabsf(nf.x - cf.x) + fabsf(nf.y - cf.y) + fabsf(nf.z - cf.z);
                if (keepW) d += fabsf(nf.w - cf.w);
                sRight += d;
            }
        }
    }

    #pragma unroll
    for (int off = 1; off < 64; off <<= 1) {
        sUp    += __shfl_xor(sUp, off, 64);
        sDown  += __shfl_xor(sDown, off, 64);
        sLeft  += __shfl_xor(sLeft, off, 64);
        sRight += __shfl_xor(sRight, off, 64);
    }

    // -------- Phase C: store the special float4s (merge shared L/R quads)
    const int lUp    = __builtin_amdgcn_readfirstlane(((n - 64) >> 2) & 63);
    const int lDown  = __builtin_amdgcn_readfirstlane(((n + 64) >> 2) & 63);
    const int lLeft  = __builtin_amdgcn_readfirstlane(((n - 1)  >> 2) & 63);
    const int lRight = __builtin_amdgcn_readfirstlane(((n + 1)  >> 2) & 63);

    const int compUD = n & 3;          // (n±64)&3 == n&3
    const int compL  = (n - 1) & 3;
    const int compR  = (n + 1) & 3;

    float4 pUp, pDown, pLeft, pRight;
    pUp.x    = compUD == 0 ? sUp : 0.f;    pUp.y    = compUD == 1 ? sUp : 0.f;
    pUp.z    = compUD == 2 ? sUp : 0.f;    pUp.w    = compUD == 3 ? sUp : 0.f;
    pDown.x  = compUD == 0 ? sDown : 0.f;  pDown.y  = compUD == 1 ? sDown : 0.f;
    pDown.z  = compUD == 2 ? sDown : 0.f;  pDown.w  = compUD == 3 ? sDown : 0.f;
    pLeft.x  = compL == 0 ? sLeft : 0.f;   pLeft.y  = compL == 1 ? sLeft : 0.f;
    pLeft.z  = compL == 2 ? sLeft : 0.f;   pLeft.w  = compL == 3 ? sLeft : 0.f;
    pRight.x = compR == 0 ? sRight : 0.f;  pRight.y = compR == 1 ? sRight : 0.f;
    pRight.z = compR == 2 ? sRight : 0.f;  pRight.w = compR == 3 ? sRight : 0.f;

    #pragma unroll
    for (int k = 0; k < 16; ++k) {
        if (k == kUp || k == kDown || k == kLeft || k == kRight) {
            float4 v = z;
            if (k == kUp    && lane == lUp)    { v.x += pUp.x;    v.y += pUp.y;    v.z += pUp.z;    v.w += pUp.w;    }
            if (k == kDown  && lane == lDown)  { v.x += pDown.x;  v.y += pDown.y;  v.z += pDown.z;  v.w += pDown.w;  }
            if (k == kLeft  && lane == lLeft)  { v.x += pLeft.x;  v.y += pLeft.y;  v.z += pLeft.z;  v.w += pLeft.w;  }
            if (k == kRight && lane == lRight) { v.x += pRight.x; v.y += pRight.y; v.z += pRight.z; v.w += pRight.w; }
            rowp[k * 64 + lane] = v;
        }
    }
}

extern "C" void kernel_launch(void* const* d_in, const int* in_sizes, int n_in,
                              void* d_out, int out_size, void* d_ws, size_t ws_size,
                              hipStream_t stream) {
    const float* data = (const float*)d_in[0];
    float* out = (float*)d_out;
    fused2<<<ROW_BLOCKS + COPY_BLOCKS, 256, 0, stream>>>(data, out);
}

// Round 6
// 355.569 us; speedup vs baseline: 1.0358x; 1.0358x over previous
//
#include <hip/hip_runtime.h>

// data: [4, 3, 1024, 1024] fp32; NX=64, scale=16, ny=64, N=4096, p=15
// out = concat(A[4,4096,4096], data) flat fp32
#define BB 4
#define CC 3
#define HH 1024
#define WW 1024
#define NXG 64
#define NYG 64
#define SCALE 16
#define PP 15
#define NNODE 4096

static const long long A_ELEMS    = (long long)BB * NNODE * NNODE;   // 67,108,864
static const long long DATA_ELEMS = (long long)BB * CC * HH * WW;    // 12,582,912

#define NV_PER_B 4032          // 63*64 vertical edges per batch
#define NH_PER_B 4032          // 64*63 horizontal edges per batch
#define NV_TOT   16128         // BB * NV_PER_B
#define NE_TOT   32256

#define COPY_BLOCKS 512
#define EDGE_BLOCKS 8064       // 32256 edge-waves / 4 per block

// After hipMemsetAsync zeros A at fill speed, this kernel:
//  - blocks [0,512): copy data -> out tail (float4 grid-stride)
//  - blocks [512,...): one wave per edge; float4 gathers, butterfly
//    reduction, then two scattered dword stores into A (symmetric pair).
__global__ __launch_bounds__(256) void edge_copy_scatter(const float* __restrict__ data,
                                                         float* __restrict__ out) {
    if (blockIdx.x < COPY_BLOCKS) {
        long long i = (long long)blockIdx.x * 256 + threadIdx.x;
        const long long stride = (long long)COPY_BLOCKS * 256;
        const float4* __restrict__ src = (const float4*)data;
        float4* __restrict__ dst = (float4*)(out + A_ELEMS);
        const long long nvec = DATA_ELEMS / 4;
        for (; i < nvec; i += stride) dst[i] = src[i];
        return;
    }

    const int wave = (blockIdx.x - COPY_BLOCKS) * 4 + (threadIdx.x >> 6);
    const int lane = threadIdx.x & 63;
    const int r = lane >> 2;      // patch row 0..15 (15 inactive)
    const int q = lane & 3;       // float4 quad in the 16-wide cell

    int b, y, x, n_lo, n_hi;
    long long delta;              // other cell = this cell + delta floats
    if (wave < NV_TOT) {
        const int e = wave;
        b = e / NV_PER_B; const int rem = e - b * NV_PER_B;
        y = rem >> 6; x = rem & 63;                 // edge (y,x)<->(y+1,x)
        delta = (long long)SCALE * WW;
        n_lo = y * NXG + x; n_hi = n_lo + NXG;
    } else {
        const int e = wave - NV_TOT;
        b = e / NH_PER_B; const int rem = e - b * NH_PER_B;
        y = rem / 63; x = rem - y * 63;             // edge (y,x)<->(y,x+1)
        delta = SCALE;
        n_lo = y * NXG + x; n_hi = n_lo + 1;
    }

    const float* p0 = data + (((long long)(b * CC)) * HH + (long long)y * SCALE + r) * WW
                           + x * SCALE + q * 4;
    float s = 0.f;
    if (r < PP) {
        #pragma unroll
        for (int c = 0; c < CC; ++c) {
            const float* p = p0 + (long long)c * HH * WW;
            const float4 a  = *(const float4*)p;
            const float4 nb = *(const float4*)(p + delta);
            float d = fabsf(nb.x - a.x) + fabsf(nb.y - a.y) + fabsf(nb.z - a.z);
            if (q != 3) d += fabsf(nb.w - a.w);     // col 15 excluded
            s += d;
        }
    }
    #pragma unroll
    for (int off = 32; off; off >>= 1) s += __shfl_down(s, off, 64);

    if (lane == 0) {
        float* Ab = out + (long long)b * NNODE * NNODE;
        Ab[(long long)n_hi * NNODE + n_lo] = s;
        Ab[(long long)n_lo * NNODE + n_hi] = s;
    }
}

extern "C" void kernel_launch(void* const* d_in, const int* in_sizes, int n_in,
                              void* d_out, int out_size, void* d_ws, size_t ws_size,
                              hipStream_t stream) {
    const float* data = (const float*)d_in[0];
    float* out = (float*)d_out;

    // Zero the A region via the runtime's optimized fill path (graph-legal
    // memset node, ~6.3 TB/s). Stream order guarantees it completes before
    // the edge scatters below.
    hipMemsetAsync(out, 0, (size_t)A_ELEMS * sizeof(float), stream);

    edge_copy_scatter<<<COPY_BLOCKS + EDGE_BLOCKS, 256, 0, stream>>>(data, out);
}